// Round 4
// baseline (244.241 us; speedup 1.0000x reference)
//
#include <hip/hip_runtime.h>
#include <cstdint>
#include <cstddef>

// ---- problem constants ----
#define NBATCH   16384
#define NSEC     9
#define NOC      50        // conv output channels per section
#define NOCP     64        // padded to 4 MFMA n-tiles
#define KPAD     256       // padded K for 8 x 32 MFMA steps
#define KREAL    240
#define XROW     1640      // 41*40 floats per batch
#define XUNITS   208       // 16B-units per LDS row (205 real + 3 zero pad)
#define XSF      1664      // f16 elems per LDS row = XUNITS*8
#define TB       16        // batches per block
#define NTILES   1024      // 16384/16
#define TILEF16  26624     // f16 elems per staged tile = 16*1664 (53248 B)
#define WELEMS   147456    // 9*64*256
#define WBLOCKS  576       // WELEMS/256
#define OUTHALF  7372800   // 16384*50*9
#define THRESH   6.2f

typedef _Float16 half8  __attribute__((ext_vector_type(8)));
typedef _Float16 half4v __attribute__((ext_vector_type(4)));
typedef float    f32x4  __attribute__((ext_vector_type(4)));

#define GLD_LDS16(gsrc, ldst)                                                  \
    __builtin_amdgcn_global_load_lds(                                          \
        (const __attribute__((address_space(1))) void*)(gsrc),                 \
        (__attribute__((address_space(3))) void*)(ldst), 16, 0, 0)

// ---- prep: W fp32 -> f16 [9][64][256] zero-padded, AND x fp32 -> f16
//      pre-swizzled per-16-batch tiles matching the fused kernel's LDS
//      layout byte-for-byte (so staging can be a raw LDS DMA). ----
__global__ __launch_bounds__(256)
void prep_kernel(const float* __restrict__ x, const float* __restrict__ W,
                 _Float16* __restrict__ wks, _Float16* __restrict__ x16) {
    const int blk = blockIdx.x, tid = threadIdx.x;
    if (blk < WBLOCKS) {
        int idx = blk * 256 + tid;
        int k   = idx & 255;
        int ocp = (idx >> 8) & 63;
        int sec = idx >> 14;
        float v = 0.0f;
        if (ocp < NOC && k < KREAL)
            v = W[(size_t)(sec * NOC + ocp) * KREAL + k];
        wks[idx] = (_Float16)v;
        return;
    }
    const int b2   = blk - WBLOCKS;      // 0 .. 13311
    const int tile = b2 / 13;            // 13 blocks per tile (13*256 == 16*208)
    const int rem  = (b2 - tile * 13) * 256 + tid;   // 0 .. 3327
    const int brow = rem / XUNITS;
    const int slot = rem - brow * XUNITS;
    const int u    = slot ^ (brow & 7);  // data unit stored at this slot
    half8 h = {};
    if (u < 205) {                       // 205*8 == 1640 exactly
        const float* src = x + ((size_t)tile * TB + brow) * XROW + u * 8;
        float4 a = *(const float4*)src;
        float4 b = *(const float4*)(src + 4);
        h[0] = (_Float16)a.x; h[1] = (_Float16)a.y;
        h[2] = (_Float16)a.z; h[3] = (_Float16)a.w;
        h[4] = (_Float16)b.x; h[5] = (_Float16)b.y;
        h[6] = (_Float16)b.z; h[7] = (_Float16)b.w;
    }
    *(half8*)(x16 + (size_t)tile * TILEF16 + (size_t)rem * 8) = h;
}

// ---- fused: stage tile by LDS-DMA; waves own section subsets (3/2/2/2);
//      n-loop inside wave so each A fragment feeds 4 MFMAs from registers ----
__global__ __launch_bounds__(256, 3)
void fused_dma_kernel(const _Float16* __restrict__ x16,
                      const _Float16* __restrict__ wks,
                      float* __restrict__ out) {
    __shared__ __align__(16) _Float16 xs[TB * XSF];   // 53248 B

    const int tid  = threadIdx.x;
    const int lane = tid & 63;
    const int w    = tid >> 6;
    const size_t b0 = (size_t)blockIdx.x * TB;

    // ---- staging: 52 x 1KB chunks, 13 per wave, zero VGPR round-trip ----
    {
        const _Float16* xt = x16 + (size_t)blockIdx.x * TILEF16;
        #pragma unroll
        for (int i = 0; i < 13; ++i) {
            const int c = w * 13 + i;             // chunk id, wave-uniform
            GLD_LDS16(xt + c * 512 + lane * 8, xs + c * 512);
        }
    }
    __syncthreads();   // compiler drains vmcnt before s_barrier

    const int l15  = lane & 15;
    const int quad = lane >> 4;
    const int sw   = l15 & 7;

    const _Float16* arow = xs + l15 * XSF;
    // section split across waves: 3/2/2/2
    const int s0 = (w == 0) ? 0 : (2 * w + 1);
    const int ns = (w == 0) ? 3 : 2;

    half4v res16[3][4];    // per-section, per-ntile pooled maxima (f16)

    #pragma unroll
    for (int si = 0; si < 3; ++si) {
        if (si < ns) {
            const int s = s0 + si;
            const _Float16* wsec = wks + ((size_t)s * NOCP + l15) * KPAD + quad * 8;
            const int su = s * 20 + quad;
            f32x4 acc[4][4] = {};
            #pragma unroll
            for (int kk = 0; kk < 8; ++kk) {
                half8 av[4], bv[4];
                #pragma unroll
                for (int h = 0; h < 4; ++h) {
                    int unit = su + h * 5 + kk * 4;
                    av[h] = *(const half8*)(arow + ((unit ^ sw) << 3));
                }
                #pragma unroll
                for (int n = 0; n < 4; ++n)
                    bv[n] = *(const half8*)(wsec + n * 16 * KPAD + kk * 32);
                #pragma unroll
                for (int h = 0; h < 4; ++h)
                    #pragma unroll
                    for (int n = 0; n < 4; ++n)
                        acc[h][n] = __builtin_amdgcn_mfma_f32_16x16x32_f16(
                                        av[h], bv[n], acc[h][n], 0, 0, 0);
            }
            #pragma unroll
            for (int n = 0; n < 4; ++n) {
                half4v r;
                #pragma unroll
                for (int j = 0; j < 4; ++j)
                    r[j] = (_Float16)fmaxf(
                               fmaxf(acc[0][n][j], acc[1][n][j]),
                               fmaxf(acc[2][n][j], acc[3][n][j]));
                res16[si][n] = r;
            }
        }
    }

    // ---- epilogue: scatter to LDS transpose buffer, coalesced write ----
    __syncthreads();
    float* t = (float*)xs;   // 16*450*4 = 28800 B < 53248
    #pragma unroll
    for (int si = 0; si < 3; ++si) {
        if (si < ns) {
            const int s = s0 + si;
            #pragma unroll
            for (int n = 0; n < 4; ++n) {
                const int oc = n * 16 + l15;
                if (oc < NOC) {
                    #pragma unroll
                    for (int j = 0; j < 4; ++j)
                        t[(quad * 4 + j) * 450 + oc * 9 + s] =
                            (float)res16[si][n][j];
                }
            }
        }
    }
    __syncthreads();

    const size_t ob = b0 * 450;
    for (int i = tid; i < TB * 450; i += 256) {
        float v = t[i];
        out[ob + i] = v;
        out[OUTHALF + ob + i] = (v > THRESH) ? 1.0f : 0.0f;
    }
}

// ---- mid fallback (ws fits W only): R3's verified register-staged kernel ----
__global__ __launch_bounds__(256, 3)
void fused_reg_kernel(const float* __restrict__ x,
                      const _Float16* __restrict__ wks,
                      float* __restrict__ out) {
    __shared__ __align__(16) _Float16 xs[TB * XSF];
    const int tid = threadIdx.x;
    const size_t b0 = (size_t)blockIdx.x * TB;
    {
        const int bb  = tid >> 4;
        const int u16 = tid & 15;
        const int swb = bb & 7;
        const float* xrow = x + (b0 + bb) * XROW;
        _Float16* lrow = xs + bb * XSF;
        #pragma unroll
        for (int jj = 0; jj < 13; ++jj) {
            int u = u16 + 16 * jj;
            half8 h = {};
            if (u < 205) {
                float4 va = *(const float4*)(xrow + u * 8);
                float4 vb = *(const float4*)(xrow + u * 8 + 4);
                h[0] = (_Float16)va.x; h[1] = (_Float16)va.y;
                h[2] = (_Float16)va.z; h[3] = (_Float16)va.w;
                h[4] = (_Float16)vb.x; h[5] = (_Float16)vb.y;
                h[6] = (_Float16)vb.z; h[7] = (_Float16)vb.w;
            }
            *(half8*)(lrow + ((u ^ swb) << 3)) = h;
        }
    }
    __syncthreads();
    const int lane = tid & 63;
    const int w    = tid >> 6;
    const int l15  = lane & 15;
    const int quad = lane >> 4;
    const int sw   = l15 & 7;
    const _Float16* arow = xs + l15 * XSF;
    const _Float16* wrow = wks + (size_t)(w * 16 + l15) * KPAD + quad * 8;
    f32x4 res[NSEC];
    for (int s = 0; s < NSEC; ++s) {
        const _Float16* wsec = wrow + (size_t)s * (NOCP * KPAD);
        half8 bv[8];
        #pragma unroll
        for (int kk = 0; kk < 8; ++kk)
            bv[kk] = *(const half8*)(wsec + kk * 32);
        f32x4 acc[4] = {f32x4{}, f32x4{}, f32x4{}, f32x4{}};
        const int su = s * 20 + quad;
        #pragma unroll
        for (int kk = 0; kk < 8; ++kk)
            #pragma unroll
            for (int h = 0; h < 4; ++h) {
                int unit = su + h * 5 + kk * 4;
                half8 av = *(const half8*)(arow + ((unit ^ sw) << 3));
                acc[h] = __builtin_amdgcn_mfma_f32_16x16x32_f16(
                             av, bv[kk], acc[h], 0, 0, 0);
            }
        f32x4 r;
        #pragma unroll
        for (int j = 0; j < 4; ++j)
            r[j] = fmaxf(fmaxf(acc[0][j], acc[1][j]),
                         fmaxf(acc[2][j], acc[3][j]));
        res[s] = r;
    }
    __syncthreads();
    float* t = (float*)xs;
    const int oc = w * 16 + l15;
    if (oc < NOC) {
        #pragma unroll
        for (int s = 0; s < NSEC; ++s)
            #pragma unroll
            for (int r = 0; r < 4; ++r)
                t[(quad * 4 + r) * 450 + oc * 9 + s] = res[s][r];
    }
    __syncthreads();
    const size_t ob = b0 * 450;
    for (int i = tid; i < TB * 450; i += 256) {
        float v = t[i];
        out[ob + i] = v;
        out[OUTHALF + ob + i] = (v > THRESH) ? 1.0f : 0.0f;
    }
}

// ---- last-resort fallback: direct fp32 ----
__global__ __launch_bounds__(256)
void naive_kernel(const float* __restrict__ x, const float* __restrict__ W,
                  float* __restrict__ out) {
    size_t idx = (size_t)blockIdx.x * 256 + threadIdx.x;
    if (idx >= OUTHALF) return;
    int s  = (int)(idx % NSEC);
    int oc = (int)((idx / NSEC) % NOC);
    int b  = (int)(idx / (NSEC * NOC));
    const float* xb = x + (size_t)b * XROW + s * 160;
    const float* wv = W + (size_t)(s * NOC + oc) * KREAL;
    float best = -1e30f;
    for (int h0 = 0; h0 < 4; ++h0) {
        float acc = 0.0f;
        for (int k = 0; k < KREAL; ++k)
            acc += xb[h0 * 40 + k] * wv[k];
        best = fmaxf(best, acc);
    }
    out[idx] = best;
    out[OUTHALF + idx] = (best > THRESH) ? 1.0f : 0.0f;
}

extern "C" void kernel_launch(void* const* d_in, const int* in_sizes, int n_in,
                              void* d_out, int out_size, void* d_ws, size_t ws_size,
                              hipStream_t stream) {
    const float* x = (const float*)d_in[0];   // [16384,1,41,40]
    const float* W = (const float*)d_in[1];   // [9,50,1,6,40]
    float* out = (float*)d_out;               // pots(7372800) ++ spks(7372800)

    const size_t w_bytes   = (size_t)WELEMS * sizeof(_Float16);              // 294912
    const size_t x16_bytes = (size_t)NTILES * TILEF16 * sizeof(_Float16);    // 54525952

    if (ws_size >= w_bytes + x16_bytes) {
        _Float16* wks = (_Float16*)d_ws;
        _Float16* x16 = (_Float16*)((char*)d_ws + w_bytes);
        prep_kernel<<<WBLOCKS + NTILES * 13, 256, 0, stream>>>(x, W, wks, x16);
        fused_dma_kernel<<<NTILES, 256, 0, stream>>>(x16, wks, out);
    } else if (ws_size >= w_bytes) {
        _Float16* wks = (_Float16*)d_ws;
        prep_kernel<<<WBLOCKS, 256, 0, stream>>>(x, W, wks, nullptr);
        fused_reg_kernel<<<NBATCH / TB, 256, 0, stream>>>(x, wks, out);
    } else {
        naive_kernel<<<(OUTHALF + 255) / 256, 256, 0, stream>>>(x, W, out);
    }
}